// Round 7
// baseline (656.905 us; speedup 1.0000x reference)
//
#include <hip/hip_runtime.h>
#include <hip/hip_bf16.h>
#include <math.h>

using frag8 = __attribute__((ext_vector_type(8))) short;
using f32x4 = __attribute__((ext_vector_type(4))) float;

#define BM 256
#define BN 256

typedef const __attribute__((address_space(1))) unsigned char glb_u8;
typedef __attribute__((address_space(3))) unsigned char lds_u8;

__device__ __forceinline__ float b2f(unsigned short v) {
    union { unsigned u; float f; } x; x.u = ((unsigned)v) << 16; return x.f;
}
__device__ __forceinline__ unsigned short f2b(float f) {
    union { float f; unsigned u; } x; x.f = f;
    unsigned u = x.u;
    u += 0x7fffu + ((u >> 16) & 1u);   // RNE
    return (unsigned short)(u >> 16);
}

// ---------------- merged prep: cast x->bf16 + transpose/cast both weights ----------------
// blockIdx ranges: [0,16384) cast (8 elems/thread); [16384,19456) W_in transpose
// (orig grid 96x32); [19456,20480) W_out transpose (orig 32x32). All 256-thr
// blocks; branch is block-uniform. Saves 2 dispatches + gaps vs 3 kernels.
__global__ __launch_bounds__(256) void prep_kernel(
    const float* __restrict__ x, unsigned short* __restrict__ xb,
    const float* __restrict__ W_in, unsigned short* __restrict__ Wint,
    const float* __restrict__ W_out, unsigned short* __restrict__ Wot) {
    __shared__ float tile[32][33];
    const int bx = blockIdx.x;
    const int tid = threadIdx.x;
    if (bx < 16384) {
        long i = ((long)bx * 256 + tid) * 8;
        float4 a = *(const float4*)(x + i);
        float4 b = *(const float4*)(x + i + 4);
        struct alignas(16) U8 { unsigned short s[8]; } o;
        o.s[0] = f2b(a.x); o.s[1] = f2b(a.y); o.s[2] = f2b(a.z); o.s[3] = f2b(a.w);
        o.s[4] = f2b(b.x); o.s[5] = f2b(b.y); o.s[6] = f2b(b.z); o.s[7] = f2b(b.w);
        *(U8*)(xb + i) = o;
    } else {
        const float* in; unsigned short* out; int Ccols, cb, rb;
        if (bx < 16384 + 3072) {
            int bb = bx - 16384;
            in = W_in; out = Wint; Ccols = 3072;
            cb = (bb % 96) * 32; rb = (bb / 96) * 32;
        } else {
            int bb = bx - 16384 - 3072;
            in = W_out; out = Wot; Ccols = 1024;
            cb = (bb & 31) * 32; rb = (bb >> 5) * 32;
        }
        const int R = 1024;   // rows of input = d
        int tx = tid & 31, ty = tid >> 5;
        for (int r = ty; r < 32; r += 8)
            tile[r][tx] = in[(size_t)(rb + r) * Ccols + cb + tx];
        __syncthreads();
        for (int r = ty; r < 32; r += 8)
            out[(size_t)(cb + r) * R + rb + tx] = f2b(tile[tx][r]);
    }
}

// ---------------- bf16 MFMA GEMM: C[M,N] = A[M,K] * Bt[N,K]^T ----------------
// R1 ring-4 structure (best measured: 676 TF on GEMM1). K consumed in 32-wide
// units; LDS holds 4 units (A 16KB + B 16KB each = 128 KiB). Each iteration
// stages unit t+3 (4x global_load_lds 16B), computes unit t as two 16-MFMA
// clusters under setprio(1), then ONE counted s_waitcnt vmcnt(8) + barrier:
// 12 loads (3 units) stay in flight across the barrier, only the oldest unit
// drains -> never vmcnt(0) in steady state. LDS rows pair-interleaved (two 64B
// rows per 128B line) with chunk-XOR swizzle (applied on the pre-swizzled
// global SOURCE; read side same XOR) -> 0 bank conflicts measured.
// mode 0: store fp32 to Cf
// mode 1: N==3072 split epilogue (block-uniform segment): V=gelu, Q=gelu,
//         Lam=lb+(1-lb)*sigmoid, all bf16.
__global__ __launch_bounds__(512, 2) void gemm_bf16(
    const unsigned short* __restrict__ A, const unsigned short* __restrict__ Bt,
    int M, int N, int K, int mode,
    float* __restrict__ Cf,
    unsigned short* __restrict__ Vp, unsigned short* __restrict__ Qp,
    unsigned short* __restrict__ Lp, const float* __restrict__ lb) {
    __shared__ __align__(16) char smem[131072];   // 4 units x (16KB A + 16KB B)

    const int tid = threadIdx.x;
    const int lane16 = tid & 15;
    const int quad = (tid >> 4) & 3;
    const int wave = tid >> 6;
    const int wm = wave >> 2;        // 0..1 -> 128-row half
    const int wn = wave & 3;         // 0..3 -> 64-col slice

    // XCD-aware bijective swizzle (nwg % 8 == 0 for both our launches)
    const int nbx = N / BN;
    const int nwg = (int)gridDim.x;
    const int sw = ((int)blockIdx.x & 7) * (nwg >> 3) + ((int)blockIdx.x >> 3);
    const long m0 = (long)(sw / nbx) * BM;
    const long n0 = (long)(sw % nbx) * BN;
    const long K2 = (long)K * 2;

    // ---- staging addresses (identical pattern for A and B) ----
    // load L in {0,1} writes LDS bytes [L*8192 + tid*16, +16) of the unit region.
    // line = off/128, chunk c = (off/16)&7; logical chunk c0 = c ^ (line&7);
    // line i holds rows {2i, 2i+1}: c0 = rowpar*4 + kblk (kblk = 8-elem group of k).
    const int c0 = (tid & 7) ^ ((tid >> 3) & 7);
    long srcL0, srcL1; int dstL0, dstL1;
    {
        const int kk2 = (c0 & 3) << 4;                      // byte offset of k-group
        const int r0 = ((tid >> 3) << 1) + (c0 >> 2);       // rows 0..127
        const int r1 = ((64 + (tid >> 3)) << 1) + (c0 >> 2);// rows 128..255
        srcL0 = (long)r0 * K2 + kk2;
        srcL1 = (long)r1 * K2 + kk2;
        dstL0 = tid * 16;
        dstL1 = 8192 + tid * 16;
    }
    const char* Ab = (const char*)A + m0 * K2;
    const char* Bb = (const char*)Bt + n0 * K2;

    // ---- fragment read offsets within a unit (bytes), constant across K ----
    int offA[8], offB[4];
#pragma unroll
    for (int mf = 0; mf < 8; ++mf) {
        int row = wm * 128 + mf * 16 + lane16;
        int line = row >> 1;
        int c = (((row & 1) << 2) | quad) ^ (line & 7);
        offA[mf] = line * 128 + c * 16;
    }
#pragma unroll
    for (int nf = 0; nf < 4; ++nf) {
        int row = wn * 64 + nf * 16 + lane16;
        int line = row >> 1;
        int c = (((row & 1) << 2) | quad) ^ (line & 7);
        offB[nf] = 16384 + line * 128 + c * 16;
    }

    f32x4 acc[8][4];
#pragma unroll
    for (int i = 0; i < 8; ++i)
#pragma unroll
        for (int j = 0; j < 4; ++j) acc[i][j] = (f32x4){0.f, 0.f, 0.f, 0.f};

#define STAGE(u) do { \
        char* ldb = smem + ((u) & 3) * 32768; \
        long kb = (long)(u) * 64; \
        __builtin_amdgcn_global_load_lds((glb_u8*)(Ab + srcL0 + kb), (lds_u8*)(ldb + dstL0), 16, 0, 0); \
        __builtin_amdgcn_global_load_lds((glb_u8*)(Ab + srcL1 + kb), (lds_u8*)(ldb + dstL1), 16, 0, 0); \
        __builtin_amdgcn_global_load_lds((glb_u8*)(Bb + srcL0 + kb), (lds_u8*)(ldb + 16384 + dstL0), 16, 0, 0); \
        __builtin_amdgcn_global_load_lds((glb_u8*)(Bb + srcL1 + kb), (lds_u8*)(ldb + 16384 + dstL1), 16, 0, 0); \
    } while (0)

    const int NT = K >> 5;   // 32-wide K-units
    // prologue: fill 3 units of the ring; drain only the oldest
    STAGE(0); STAGE(1); STAGE(2);
    asm volatile("s_waitcnt vmcnt(8)" ::: "memory");
    __builtin_amdgcn_s_barrier();

    for (int t = 0; t < NT; ++t) {
        if (t + 3 < NT) STAGE(t + 3);
        const char* ub = smem + (t & 3) * 32768;
        frag8 bfr[4], af[4];
#pragma unroll
        for (int nf = 0; nf < 4; ++nf) bfr[nf] = *(const frag8*)(ub + offB[nf]);
#pragma unroll
        for (int mf = 0; mf < 4; ++mf) af[mf] = *(const frag8*)(ub + offA[mf]);
        __builtin_amdgcn_s_setprio(1);
#pragma unroll
        for (int mf = 0; mf < 4; ++mf)
#pragma unroll
            for (int nf = 0; nf < 4; ++nf)
                acc[mf][nf] = __builtin_amdgcn_mfma_f32_16x16x32_bf16(af[mf], bfr[nf], acc[mf][nf], 0, 0, 0);
        __builtin_amdgcn_s_setprio(0);
#pragma unroll
        for (int mf = 0; mf < 4; ++mf) af[mf] = *(const frag8*)(ub + offA[4 + mf]);
        __builtin_amdgcn_s_setprio(1);
#pragma unroll
        for (int mf = 0; mf < 4; ++mf)
#pragma unroll
            for (int nf = 0; nf < 4; ++nf)
                acc[4 + mf][nf] = __builtin_amdgcn_mfma_f32_16x16x32_bf16(af[mf], bfr[nf], acc[4 + mf][nf], 0, 0, 0);
        __builtin_amdgcn_s_setprio(0);
        // counted fence: guarantee unit t+1 landed; keep 2 units in flight
        if (t < NT - 3)       { asm volatile("s_waitcnt vmcnt(8)" ::: "memory"); }
        else if (t == NT - 3) { asm volatile("s_waitcnt vmcnt(4)" ::: "memory"); }
        else if (t == NT - 2) { asm volatile("s_waitcnt vmcnt(0)" ::: "memory"); }
        __builtin_amdgcn_s_barrier();
    }
#undef STAGE

    if (mode == 0) {
#pragma unroll
        for (int mf = 0; mf < 8; ++mf)
#pragma unroll
            for (int nf = 0; nf < 4; ++nf) {
                long col = n0 + wn * 64 + nf * 16 + lane16;
#pragma unroll
                for (int r = 0; r < 4; ++r) {
                    long row = m0 + wm * 128 + mf * 16 + quad * 4 + r;
                    Cf[row * N + col] = acc[mf][nf][r];
                }
            }
    } else {
        // block-uniform segment: BN=256 divides 1024, so each block is in one segment
        const int seg = (int)(n0 >> 10);            // 0=V, 1=Q, 2=Lam
        const int cbase = (int)(n0 & 1023) + wn * 64;
        unsigned short* dst = (seg == 0) ? Vp : (seg == 1 ? Qp : Lp);
#pragma unroll
        for (int mf = 0; mf < 8; ++mf)
#pragma unroll
            for (int nf = 0; nf < 4; ++nf) {
                int col = cbase + nf * 16 + lane16;
#pragma unroll
                for (int r = 0; r < 4; ++r) {
                    long row = m0 + wm * 128 + mf * 16 + quad * 4 + r;
                    float v = acc[mf][nf][r];
                    float res;
                    if (seg < 2) {
                        // tanh-form gelu: x * sigmoid(1.5958*x*(1+0.044715 x^2))
                        float u = 1.59576912f * v * (1.0f + 0.044715f * v * v);
                        res = v / (1.0f + __expf(-u));
                    } else {
                        float sg = 1.0f / (1.0f + __expf(-v));
                        float l = lb[col];
                        res = l + (1.0f - l) * sg;
                    }
                    dst[row * 1024 + col] = f2b(res);
                }
            }
    }
}

// ---------------- scan phase 1: per-(chain,chunk) local state + decay product ----------------
// Constexpr trip count + unroll-8: the 2 loads/iter are independent of the FMA
// recurrence, so unrolling batches 16 loads in flight per thread instead of
// serializing ~500-cycle latencies. FP order unchanged (same fmaf sequence).
__global__ __launch_bounds__(256) void scan_phase1(
    const unsigned short* __restrict__ lam, const unsigned short* __restrict__ V,
    float* __restrict__ Sl, float* __restrict__ P) {
    constexpr int L = 64;
    int cid = blockIdx.x * 256 + threadIdx.x;  // 0..4095
    int c = blockIdx.y;
    int bi = cid >> 9, h = cid & 511;
    float s00 = 0, s01 = 0, s10 = 0, s11 = 0, p0 = 1.f, p1 = 1.f;
    const int t0 = c * L;
    const unsigned* lamp = (const unsigned*)lam;
    const unsigned* vp = (const unsigned*)V;
    const long base0 = ((long)t0 * 8 + bi) * 512 + h;
#pragma unroll 8
    for (int tt = 0; tt < L; ++tt) {
        long idx = base0 + (long)tt * 4096;
        unsigned lu = lamp[idx], vu = vp[idx];
        float la0 = b2f((unsigned short)lu), la1 = b2f((unsigned short)(lu >> 16));
        float v0 = b2f((unsigned short)vu), v1 = b2f((unsigned short)(vu >> 16));
        float k0 = 1.f - la0, k1 = 1.f - la1;
        s00 = fmaf(la0, s00, k0 * v0); s01 = fmaf(la0, s01, k0 * v1);
        s10 = fmaf(la1, s10, k1 * v0); s11 = fmaf(la1, s11, k1 * v1);
        p0 *= la0; p1 *= la1;
    }
    long base = (long)c * 4096 + cid;
    ((float4*)Sl)[base] = make_float4(s00, s01, s10, s11);
    ((float2*)P)[base] = make_float2(p0, p1);
}

// ---------------- scan phase 2+3 fused: prefix combine + replay, emit o ----------------
// Each (chunk c, cid) thread redoes its own exclusive prefix over chunks < c
// reading Sl/P (6 MB total, L2-resident) with the IDENTICAL fmaf sequence the
// old phase2 used -> same FP result, no Sini round-trip, one fewer dispatch
// (and the old scan2 ran at 64 blocks = 25% CU occupancy).
__global__ __launch_bounds__(256) void scan_phase3(
    const unsigned short* __restrict__ lam, const unsigned short* __restrict__ V,
    const unsigned short* __restrict__ Q,
    const float* __restrict__ Sl, const float* __restrict__ P,
    unsigned short* __restrict__ o) {
    constexpr int L = 64;
    int cid = blockIdx.x * 256 + threadIdx.x;
    int c = blockIdx.y;
    int bi = cid >> 9, h = cid & 511;
    float s00 = 0.f, s01 = 0.f, s10 = 0.f, s11 = 0.f;
#pragma unroll 8
    for (int c2 = 0; c2 < c; ++c2) {
        long base = (long)c2 * 4096 + cid;
        float4 slv = ((const float4*)Sl)[base];
        float2 pv  = ((const float2*)P)[base];
        s00 = fmaf(pv.x, s00, slv.x); s01 = fmaf(pv.x, s01, slv.y);
        s10 = fmaf(pv.y, s10, slv.z); s11 = fmaf(pv.y, s11, slv.w);
    }
    const int t0 = c * L;
    const unsigned* lamp = (const unsigned*)lam;
    const unsigned* vp = (const unsigned*)V;
    const unsigned* qp = (const unsigned*)Q;
    unsigned* op = (unsigned*)o;
    const long base0 = ((long)t0 * 8 + bi) * 512 + h;
#pragma unroll 8
    for (int tt = 0; tt < L; ++tt) {
        long idx = base0 + (long)tt * 4096;
        unsigned lu = lamp[idx], vu = vp[idx], qu = qp[idx];
        float la0 = b2f((unsigned short)lu), la1 = b2f((unsigned short)(lu >> 16));
        float v0 = b2f((unsigned short)vu), v1 = b2f((unsigned short)(vu >> 16));
        float q0 = b2f((unsigned short)qu), q1 = b2f((unsigned short)(qu >> 16));
        float k0 = 1.f - la0, k1 = 1.f - la1;
        s00 = fmaf(la0, s00, k0 * v0); s01 = fmaf(la0, s01, k0 * v1);
        s10 = fmaf(la1, s10, k1 * v0); s11 = fmaf(la1, s11, k1 * v1);
        float o0 = q0 * s00 + q1 * s10;
        float o1 = q0 * s01 + q1 * s11;
        op[idx] = (unsigned)f2b(o0) | ((unsigned)f2b(o1) << 16);
    }
}

extern "C" void kernel_launch(void* const* d_in, const int* in_sizes, int n_in,
                              void* d_out, int out_size, void* d_ws, size_t ws_size,
                              hipStream_t stream) {
    const float* x = (const float*)d_in[0];
    const float* lb = (const float*)d_in[1];
    const float* W_in = (const float*)d_in[2];
    const float* W_out = (const float*)d_in[3];
    float* out = (float*)d_out;

    const int n = 4096, b = 8, d = 1024;
    const long NB = (long)n * b;   // 32768 rows
    const int C = 64;              // chunks (chunk length 64; C*L == n)

    char* ws = (char*)d_ws;
    size_t off = 0;
    auto alloc = [&](size_t bytes) -> char* {
        char* p = ws + off;
        off += (bytes + 255) & ~(size_t)255;
        return p;
    };
    unsigned short* xb   = (unsigned short*)alloc(NB * d * 2);          // reused as o after GEMM1
    unsigned short* Wint = (unsigned short*)alloc((size_t)3 * d * d * 2);
    unsigned short* Wot  = (unsigned short*)alloc((size_t)d * d * 2);
    unsigned short* Vb   = (unsigned short*)alloc(NB * d * 2);
    unsigned short* Qb   = (unsigned short*)alloc(NB * d * 2);
    unsigned short* Lb   = (unsigned short*)alloc(NB * d * 2);
    float* Sl   = (float*)alloc((size_t)C * 4096 * 4 * 4);
    float* P    = (float*)alloc((size_t)C * 4096 * 2 * 4);

    // 1) merged prep: cast x -> bf16, transpose+cast W_in and W_out
    //    grid = 16384 (cast) + 3072 (W_in) + 1024 (W_out)
    prep_kernel<<<dim3(20480), 256, 0, stream>>>(x, xb, W_in, Wint, W_out, Wot);
    // 2) GEMM1 + fused activations -> V, Q, lam (bf16); 256x256 tiles, 512 threads
    const int nwg1 = (3 * d / BN) * (int)(NB / BM);   // 12 * 128 = 1536 (%8==0)
    gemm_bf16<<<dim3(nwg1), 512, 0, stream>>>(
        xb, Wint, (int)NB, 3 * d, d, 1, nullptr, Vb, Qb, Lb, lb);
    // 3) chunked scan: local states, then fused prefix+replay
    scan_phase1<<<dim3(16, C), 256, 0, stream>>>(Lb, Vb, Sl, P);
    unsigned short* ob = xb;  // xb dead after GEMM1; reuse as o
    scan_phase3<<<dim3(16, C), 256, 0, stream>>>(Lb, Vb, Qb, Sl, P, ob);
    // 4) GEMM2 -> fp32 output
    const int nwg2 = (d / BN) * (int)(NB / BM);       // 4 * 128 = 512 (%8==0)
    gemm_bf16<<<dim3(nwg2), 512, 0, stream>>>(
        ob, Wot, (int)NB, d, d, 0, out, nullptr, nullptr, nullptr, nullptr);
}